// Round 7
// baseline (389.177 us; speedup 1.0000x reference)
//
#include <hip/hip_runtime.h>

// Problem constants (fixed by the reference)
#define BATCH   64
#define NNODE   1024
#define NEDGE   16384
#define ZHDIM   128
#define EFDIM   64
#define MAXZV   13
#define MAXEFV  8
#define NEDGES_TOT (BATCH * NEDGE)        // 1,048,576
#define NCOMBO  4096                      // 8^4 feature combos
#define AROWS   (NCOMBO * 3)              // x3 sign values
#define EDGES_PER_BLOCK 16

typedef float f32x4 __attribute__((ext_vector_type(4)));

// ---------------------------------------------------------------------------
// Workspace layout (d_ws): [0, 3 MB) : A table, AROWS x 64 floats
// ---------------------------------------------------------------------------

// A[row][c] = (sum_i ef_tables[i][f_i][c]) * dV_table[s][c],  row = combo*3 + s
__global__ __launch_bounds__(256) void combine_tables_kernel(
    const float* __restrict__ ef_tables,  // (4,8,64)
    const float* __restrict__ dV_table,   // (3,64)
    float*       __restrict__ A)          // (AROWS,64)
{
    int tid = blockIdx.x * 256 + threadIdx.x;
    int row = tid >> 4;
    int c4  = tid & 15;
    int combo = row / 3;
    int s     = row - combo * 3;
    int f3 = combo & 7, f2 = (combo >> 3) & 7, f1 = (combo >> 6) & 7, f0 = (combo >> 9) & 7;

    const float4* T = (const float4*)ef_tables;   // row stride 64 floats = 16 float4
    float4 t0 = T[(0 * MAXEFV + f0) * 16 + c4];
    float4 t1 = T[(1 * MAXEFV + f1) * 16 + c4];
    float4 t2 = T[(2 * MAXEFV + f2) * 16 + c4];
    float4 t3 = T[(3 * MAXEFV + f3) * 16 + c4];
    float4 dv = ((const float4*)dV_table)[s * 16 + c4];

    float4 o;
    o.x = (t0.x + t1.x + t2.x + t3.x) * dv.x;
    o.y = (t0.y + t1.y + t2.y + t3.y) * dv.y;
    o.z = (t0.z + t1.z + t2.z + t3.z) * dv.z;
    o.w = (t0.w + t1.w + t2.w + t3.w) * dv.w;
    ((float4*)A)[row * 16 + c4] = o;
}

// Fused: per-block, 16 edges. Phase 1: threads 0..15 compute edge scalars
// into LDS. Phase 2: 16 threads/edge expand 64 channels.
// res[c] = (exp(coeff*(el-off_c)^2) * dV[sgn][c] + A[rowid][c]) * env
__global__ __launch_bounds__(256) void ef_fused_kernel(
    const float* __restrict__ pos,           // (B,N,3)
    const int*   __restrict__ edge_index,    // (B,2,E)
    const int*   __restrict__ edge_features, // (B,E,4)
    const float* __restrict__ center_pos,    // (B,N,3)
    const float* __restrict__ A,             // (AROWS,64)
    const float* __restrict__ dV_table,      // (3,64)
    float*       __restrict__ out)           // (B,E,64)
{
    __shared__ float4 s_scal[EDGES_PER_BLOCK];

    int t = threadIdx.x;
    int blk = blockIdx.x;

    if (t < EDGES_PER_BLOCK) {
        int edge = blk * EDGES_PER_BLOCK + t;
        int b = edge >> 14;               // / NEDGE
        int e = edge & (NEDGE - 1);

        int iu = edge_index[(b * 2 + 0) * NEDGE + e];
        int iv = edge_index[(b * 2 + 1) * NEDGE + e];

        const float* pu = pos + (size_t)(b * NNODE + iu) * 3;
        const float* pv = pos + (size_t)(b * NNODE + iv) * 3;
        float ux = pu[0], uy = pu[1], uz = pu[2];
        float vx = pv[0], vy = pv[1], vz = pv[2];

        float dx = ux - vx, dy = uy - vy, dz = uz - vz;
        float el = sqrtf(fmaxf(dx * dx + dy * dy + dz * dz, 1e-24f));

        // cross(posu, posv) . center_pos[idx_v]
        float cx = uy * vz - uz * vy;
        float cy = uz * vx - ux * vz;
        float cz = ux * vy - uy * vx;
        const float* cp = center_pos + (size_t)(b * NNODE + iv) * 3;
        float dV = cx * cp[0] + cy * cp[1] + cz * cp[2];
        int sgn = (dV > 0.0f) ? 2 : ((dV < 0.0f) ? 0 : 1);   // sign(dV)+1

        // envelope: P=6 -> 1 - 28 x^6 + 48 x^7 - 21 x^8, zero for x >= 1
        float x  = el * 0.1f;
        float x3 = x * x * x;
        float x6 = x3 * x3;
        float env = 1.0f - 28.0f * x6 + 48.0f * x6 * x - 21.0f * x6 * x * x;
        env = (x < 1.0f) ? env : 0.0f;

        int4 f = ((const int4*)edge_features)[edge];
        int combo = ((f.x * 8 + f.y) * 8 + f.z) * 8 + f.w;
        int rowid = combo * 3 + sgn;

        float4 o;
        o.x = el;
        o.y = env;
        o.z = __int_as_float(rowid);
        o.w = __int_as_float(sgn);
        s_scal[t] = o;
    }
    __syncthreads();

    int g   = t >> 4;                 // edge slot within block
    int c4  = t & 15;                 // float4 group within 64 channels
    int edge = blk * EDGES_PER_BLOCK + g;

    float4 sc = s_scal[g];            // LDS broadcast
    float el  = sc.x;
    float env = sc.y;
    int rowid = __float_as_int(sc.z);
    int sgn   = __float_as_int(sc.w);

    float4 a  = ((const float4*)A)[rowid * 16 + c4];
    float4 dv = ((const float4*)dV_table)[sgn * 16 + c4];

    const float step = 10.0f / 63.0f;
    // exp(coeff*d^2) = exp2(c2*d^2), c2 = -0.5/step^2 * log2(e)
    const float c2 = (-0.5f / (step * step)) * 1.44269504088896f;

    float av[4]  = {a.x, a.y, a.z, a.w};
    float dvv[4] = {dv.x, dv.y, dv.z, dv.w};
    float r[4];
#pragma unroll
    for (int k = 0; k < 4; ++k) {
        int j = c4 * 4 + k;
        float d = el - step * (float)j;
        float gs = exp2f(c2 * d * d);
        r[k] = fmaf(gs, dvv[k], av[k]) * env;
    }

    f32x4 res = {r[0], r[1], r[2], r[3]};
    // Nontemporal: keep the 268 MB output stream out of L2 so the A table
    // (3 MB, randomly gathered per edge) stays resident.
    __builtin_nontemporal_store(res, (f32x4*)out + (size_t)edge * 16 + c4);
}

// emb1: out[b,n,c] = z_tables[0][z[b,n,0]][c] + sum_{i=2..6} z_tables[i][z[b,n,i]][c]
__global__ __launch_bounds__(256) void emb1_kernel(
    const int*   __restrict__ z,         // (B,N,8)
    const float* __restrict__ z_tables,  // (8,13,128)
    float*       __restrict__ out)       // (B,N,128)
{
    int tid  = blockIdx.x * 256 + threadIdx.x;   // grid exact: 8192 blocks
    int node = tid >> 5;
    int c4   = tid & 31;

    const int* zp = z + node * 8;
    int i0 = zp[0];
    int i2 = zp[2], i3 = zp[3], i4 = zp[4], i5 = zp[5], i6 = zp[6];

    const float4* t = (const float4*)z_tables;   // row stride 128 floats = 32 float4
    float4 a0 = t[(0 * MAXZV + i0) * 32 + c4];
    float4 a2 = t[(2 * MAXZV + i2) * 32 + c4];
    float4 a3 = t[(3 * MAXZV + i3) * 32 + c4];
    float4 a4 = t[(4 * MAXZV + i4) * 32 + c4];
    float4 a5 = t[(5 * MAXZV + i5) * 32 + c4];
    float4 a6 = t[(6 * MAXZV + i6) * 32 + c4];

    f32x4 s;
    s.x = a0.x + a2.x + a3.x + a4.x + a5.x + a6.x;
    s.y = a0.y + a2.y + a3.y + a4.y + a5.y + a6.y;
    s.z = a0.z + a2.z + a3.z + a4.z + a5.z + a6.z;
    s.w = a0.w + a2.w + a3.w + a4.w + a5.w + a6.w;

    __builtin_nontemporal_store(s, (f32x4*)out + node * 32 + c4);
}

extern "C" void kernel_launch(void* const* d_in, const int* in_sizes, int n_in,
                              void* d_out, int out_size, void* d_ws, size_t ws_size,
                              hipStream_t stream) {
    const int*   z             = (const int*)  d_in[0];
    const float* pos           = (const float*)d_in[1];
    const int*   edge_index    = (const int*)  d_in[2];
    const int*   edge_features = (const int*)  d_in[3];
    const float* center_pos    = (const float*)d_in[4];
    const float* z_tables      = (const float*)d_in[5];
    const float* ef_tables     = (const float*)d_in[6];
    const float* dV_table      = (const float*)d_in[7];

    float* out_emb1 = (float*)d_out;                                  // B*N*128
    float* out_ef   = out_emb1 + (size_t)BATCH * NNODE * ZHDIM;       // B*E*64

    float* ws_A = (float*)d_ws;

    // 1. combined (ef_tables-sum * dV_table) rows: 768 blocks
    combine_tables_kernel<<<AROWS * 16 / 256, 256, 0, stream>>>(ef_tables, dV_table, ws_A);

    // 2. emb1 (independent): 8192 blocks
    emb1_kernel<<<BATCH * NNODE * 32 / 256, 256, 0, stream>>>(z, z_tables, out_emb1);

    // 3. fused edge-scalar + expansion: 65536 blocks
    ef_fused_kernel<<<NEDGES_TOT / EDGES_PER_BLOCK, 256, 0, stream>>>(
        pos, edge_index, edge_features, center_pos, ws_A, dV_table, out_ef);
}